// Round 1
// baseline (100.757 us; speedup 1.0000x reference)
//
#include <hip/hip_runtime.h>

// Problem constants (from reference):
//   spec  : (B=32, C=1, T=1000, F=481, 2) f32
//   coefs : (B=32, O=5, T=1000, NF=96, 2) f32
//   out   : same shape as spec; first NF freqs replaced by 5-tap causal
//           complex FIR over time: out[b,t,f] = sum_{n=0..4} spec[b,t+n-4,f]*coefs[b,n,t,f]
constexpr int B  = 32;
constexpr int T  = 1000;
constexpr int F  = 481;
constexpr int NF = 96;
constexpr int FS = 5;

__global__ void ldf_kernel(const float* __restrict__ spec,
                           const float* __restrict__ coefs,
                           float* __restrict__ out) {
    const int total = B * T * F;                 // 15,392,000 complex elems
    int idx = blockIdx.x * blockDim.x + threadIdx.x;
    if (idx >= total) return;

    const float2* __restrict__ sp = (const float2*)spec;
    const float2* __restrict__ cf = (const float2*)coefs;
    float2*       __restrict__ op = (float2*)out;

    int f  = idx % F;          // compiler lowers to magic-multiply (constant F)
    int bt = idx / F;
    int t  = bt % T;
    int b  = bt / T;

    float2 v;
    if (f < NF) {
        float re = 0.f, im = 0.f;
#pragma unroll
        for (int n = 0; n < FS; ++n) {
            int ts = t + n - (FS - 1);           // causal: taps t-4..t
            if (ts >= 0) {
                float2 s = sp[(b * T + ts) * F + f];
                float2 c = cf[((b * FS + n) * T + t) * NF + f];
                re = fmaf(s.x, c.x, fmaf(-s.y, c.y, re));
                im = fmaf(s.x, c.y, fmaf( s.y, c.x, im));
            }
        }
        v = make_float2(re, im);
    } else {
        v = sp[idx];                             // pass-through bins 96..480
    }
    op[idx] = v;
}

extern "C" void kernel_launch(void* const* d_in, const int* in_sizes, int n_in,
                              void* d_out, int out_size, void* d_ws, size_t ws_size,
                              hipStream_t stream) {
    const float* spec  = (const float*)d_in[0];
    const float* coefs = (const float*)d_in[1];
    float*       out   = (float*)d_out;

    const int total  = B * T * F;
    const int block  = 256;
    const int grid   = (total + block - 1) / block;
    ldf_kernel<<<grid, block, 0, stream>>>(spec, coefs, out);
}

// Round 2
// 72.553 us; speedup vs baseline: 1.3887x; 1.3887x over previous
//
#include <hip/hip_runtime.h>

// spec  : (B=32, 1, T=1000, F=481, 2) f32
// coefs : (B=32, FS=5, T=1000, NF=96, 2) f32
// out[b,t,f<96] = sum_n spec[b,t+n-4,f] * coefs[b,n,t,f]   (complex)
// out[b,t,f>=96] = spec[b,t,f]
constexpr int B  = 32;
constexpr int T  = 1000;
constexpr int F  = 481;
constexpr int NF = 96;
constexpr int FS = 5;

constexpr int FILTER_PAIRS = B * T * (NF / 2);          // 1,536,000 threads, 2 f-bins each
constexpr int COPY_ELEMS   = B * T * (F - NF);          // 12,320,000 complex elems
constexpr int COPY_PER_THR = 4;
constexpr int COPY_THREADS = COPY_ELEMS / COPY_PER_THR; // 3,080,000 (exact)
constexpr int TOTAL_THR    = FILTER_PAIRS + COPY_THREADS;

__global__ void ldf_fused(const float* __restrict__ spec,
                          const float* __restrict__ coefs,
                          float* __restrict__ out) {
    const float2* __restrict__ sp  = (const float2*)spec;
    const float4* __restrict__ cf4 = (const float4*)coefs;
    float2*       __restrict__ op  = (float2*)out;

    int gid = blockIdx.x * blockDim.x + threadIdx.x;

    if (gid < FILTER_PAIRS) {
        // ---- filter segment: blocks [0, 6000) exactly, no mixed waves ----
        int fp = gid % (NF / 2);      // f-pair index 0..47
        int bt = gid / (NF / 2);
        int t  = bt % T;
        int b  = bt / T;
        int f0 = fp * 2;

        float re0 = 0.f, im0 = 0.f, re1 = 0.f, im1 = 0.f;
#pragma unroll
        for (int n = 0; n < FS; ++n) {
            int ts = t + n - (FS - 1);               // taps t-4 .. t
            if (ts >= 0) {
                // coefs: complex idx = ((b*FS+n)*T+t)*NF + f0, even -> float4 aligned
                float4 c  = cf4[((((b * FS + n) * T + t) * NF) + f0) >> 1];
                float2 s0 = sp[(b * T + ts) * F + f0];
                float2 s1 = sp[(b * T + ts) * F + f0 + 1];
                re0 = fmaf(s0.x, c.x, fmaf(-s0.y, c.y, re0));
                im0 = fmaf(s0.x, c.y, fmaf( s0.y, c.x, im0));
                re1 = fmaf(s1.x, c.z, fmaf(-s1.y, c.w, re1));
                im1 = fmaf(s1.x, c.w, fmaf( s1.y, c.z, im1));
            }
        }
        int o = (b * T + t) * F + f0;
        op[o]     = make_float2(re0, im0);
        op[o + 1] = make_float2(re1, im1);
    } else {
        // ---- copy segment: 4 independent grid-strided float2 copies ----
        int cid = gid - FILTER_PAIRS;
        if (cid < COPY_THREADS) {
            int e[COPY_PER_THR];
#pragma unroll
            for (int k = 0; k < COPY_PER_THR; ++k) {
                int j   = cid + k * COPY_THREADS;    // lanes stay consecutive per k
                int row = j / (F - NF);
                int f   = NF + (j - row * (F - NF));
                e[k]    = row * F + f;
            }
            float2 v[COPY_PER_THR];
#pragma unroll
            for (int k = 0; k < COPY_PER_THR; ++k) v[k] = sp[e[k]];   // 4 loads in flight
#pragma unroll
            for (int k = 0; k < COPY_PER_THR; ++k) op[e[k]] = v[k];
        }
    }
}

extern "C" void kernel_launch(void* const* d_in, const int* in_sizes, int n_in,
                              void* d_out, int out_size, void* d_ws, size_t ws_size,
                              hipStream_t stream) {
    const float* spec  = (const float*)d_in[0];
    const float* coefs = (const float*)d_in[1];
    float*       out   = (float*)d_out;

    const int block = 256;
    const int grid  = (TOTAL_THR + block - 1) / block;
    ldf_fused<<<grid, block, 0, stream>>>(spec, coefs, out);
}

// Round 4
// 65.961 us; speedup vs baseline: 1.5275x; 1.0999x over previous
//
#include <hip/hip_runtime.h>

// spec  : (B=32, 1, T=1000, F=481, 2) f32
// coefs : (B=32, FS=5, T=1000, NF=96, 2) f32
// out[b,t,f<96] = sum_n spec[b,t+n-4,f] * coefs[b,n,t,f]   (complex)
// out[b,t,f>=96] = spec[b,t,f]
constexpr int B  = 32;
constexpr int T  = 1000;
constexpr int F  = 481;     // floats per row = 962, bytes per row = 3848 (8B-aligned only)
constexpr int NF = 96;
constexpr int FS = 5;

typedef float vf2 __attribute__((ext_vector_type(2)));
typedef float vf4 __attribute__((ext_vector_type(4)));

constexpr int FILTER_PAIRS   = B * T * (NF / 2);     // 1,536,000 threads, 2 f-bins each
constexpr int ROWS           = B * T;                // 32,000
constexpr int COPY_T_PER_ROW = 24;                   // 24 threads x 8 float4 = 768 floats
constexpr int COPY_THREADS   = ROWS * COPY_T_PER_ROW;        // 768,000
constexpr int TOTAL_THR      = FILTER_PAIRS + COPY_THREADS;  // 2,304,000 = 9000 * 256

__global__ void ldf_fused(const float* __restrict__ spec,
                          const float* __restrict__ coefs,
                          float* __restrict__ out) {
    const vf2* __restrict__ sp  = (const vf2*)spec;
    const vf4* __restrict__ sp4 = (const vf4*)spec;
    const vf4* __restrict__ cf4 = (const vf4*)coefs;
    vf2*       __restrict__ op  = (vf2*)out;
    vf4*       __restrict__ op4 = (vf4*)out;

    int gid = blockIdx.x * blockDim.x + threadIdx.x;

    if (gid < FILTER_PAIRS) {
        // ---- filter segment: blocks [0, 6000) exactly, no mixed waves ----
        int fp = gid % (NF / 2);      // f-pair index 0..47
        int bt = gid / (NF / 2);
        int t  = bt % T;
        int b  = bt / T;
        int f0 = fp * 2;

        float re0 = 0.f, im0 = 0.f, re1 = 0.f, im1 = 0.f;
#pragma unroll
        for (int n = 0; n < FS; ++n) {
            int ts = t + n - (FS - 1);               // taps t-4 .. t
            if (ts >= 0) {
                vf4 c  = cf4[((((b * FS + n) * T + t) * NF) + f0) >> 1];
                vf2 s0 = sp[(b * T + ts) * F + f0];
                vf2 s1 = sp[(b * T + ts) * F + f0 + 1];
                re0 = fmaf(s0.x, c.x, fmaf(-s0.y, c.y, re0));
                im0 = fmaf(s0.x, c.y, fmaf( s0.y, c.x, im0));
                re1 = fmaf(s1.x, c.z, fmaf(-s1.y, c.w, re1));
                im1 = fmaf(s1.x, c.w, fmaf( s1.y, c.z, im1));
            }
        }
        int o = (b * T + t) * F + f0;
        vf2 r0; r0.x = re0; r0.y = im0;
        vf2 r1; r1.x = re1; r1.y = im1;
        __builtin_nontemporal_store(r0, &op[o]);
        __builtin_nontemporal_store(r1, &op[o + 1]);
    } else {
        // ---- copy segment: per row, 24 threads x 8 float4 + one float2 tail ----
        int cid = gid - FILTER_PAIRS;
        if (cid < COPY_THREADS) {
            int rid = cid / COPY_T_PER_ROW;
            int k   = cid - rid * COPY_T_PER_ROW;
            // pass-through floats are [192, 962) within the row (770 floats).
            // row start (rid*962) is == 2 mod 4 for odd rows, so the 16B-aligned
            // 768-float block starts at 192 (even rows) or 194 (odd rows), and the
            // leftover float2 sits at the opposite end.
            int odd   = rid & 1;
            int basef = rid * (2 * F) + 192 + (odd << 1);   // float offset, % 4 == 0
            int fb    = (basef >> 2) + k;

            vf4 v[8];
#pragma unroll
            for (int j = 0; j < 8; ++j) v[j] = sp4[fb + COPY_T_PER_ROW * j];

            vf2 tv; int tidx = 0;
            if (k == 0) {
                int tf = rid * (2 * F) + (odd ? 192 : 960);
                tidx = tf >> 1;
                tv = sp[tidx];
            }
#pragma unroll
            for (int j = 0; j < 8; ++j)
                __builtin_nontemporal_store(v[j], &op4[fb + COPY_T_PER_ROW * j]);
            if (k == 0)
                __builtin_nontemporal_store(tv, &op[tidx]);
        }
    }
}

extern "C" void kernel_launch(void* const* d_in, const int* in_sizes, int n_in,
                              void* d_out, int out_size, void* d_ws, size_t ws_size,
                              hipStream_t stream) {
    const float* spec  = (const float*)d_in[0];
    const float* coefs = (const float*)d_in[1];
    float*       out   = (float*)d_out;

    const int block = 256;
    const int grid  = (TOTAL_THR + block - 1) / block;   // 9000
    ldf_fused<<<grid, block, 0, stream>>>(spec, coefs, out);
}